// Round 4
// baseline (295.378 us; speedup 1.0000x reference)
//
#include <hip/hip_runtime.h>

#define N_NODES 4194304
#define LEVELS  10
#define COARSE  8192
#define NNZ_E   8388608
#define NB      256      // row buckets
#define NSUB    512      // (row bucket) x (col half)
#define RB_SZ   16384    // rows per row-bucket (64 KiB LDS accumulator)
#define EPB     8192     // edges per binning block
#define CAP_SUB 17920u   // per-(bucket,half) capacity: mean 16384, +12 sigma, 512-mult

typedef int          v4i __attribute__((ext_vector_type(4)));
typedef float        v4f __attribute__((ext_vector_type(4)));
typedef unsigned int v4u __attribute__((ext_vector_type(4)));
typedef unsigned int v2u __attribute__((ext_vector_type(2)));

static __device__ __forceinline__ unsigned short f2bf(float x) {
    unsigned u = __float_as_uint(x);
    return (unsigned short)((u + 0x7FFFu + ((u >> 16) & 1u)) >> 16);
}
static __device__ __forceinline__ float bf2f(unsigned short h) {
    return __uint_as_float((unsigned)h << 16);
}

// ============ kA: HODLR moments (blocks 0..2047) + ROW-binning (2048..3071)
// Sub-bucket = (row>>14)<<1 | (col>>21): 512 segments so kE's wb-gather range
// per phase is 4 MiB (fits per-XCD L2).
// Entry: x = col(22) | rowLocal[0:9]<<22 ; y = rowLocal[10:13] | sub<<4 | bf16(val)<<16
__global__ __launch_bounds__(512) void kA(const float* __restrict__ z,
                                          float2* __restrict__ M,
                                          float* __restrict__ S,
                                          float* __restrict__ out,
                                          const int* __restrict__ rows,
                                          const int* __restrict__ cols,
                                          const float* __restrict__ vals,
                                          unsigned* __restrict__ subCtr,
                                          v2u* __restrict__ rowBinned) {
    int b = blockIdx.x, t = threadIdx.x;
    if (b < 2048) {
        if (b == 0) {
            for (int i = t; i < 2046 * 2; i += 512) S[i] = 0.f;
            if (t == 0) out[0] = 0.f;
        }
        int lane = t & 63, wave = t >> 6;
        int chunk = b * 8 + wave;
        int base = chunk * 256 + lane * 4;
        float4 zv = *(const float4*)(z + base);
        float a0 = 0.f, a1 = 0.f;
        const float* zp = (const float*)&zv;
#pragma unroll
        for (int j = 0; j < 4; ++j) {
            float p = ((float)(base + j) + 0.5f) * (1.0f / 512.0f) - 0.5f;
            p = fminf(fmaxf(p, 0.0f), (float)(COARSE - 1));
            float f = p - floorf(p);
            a0 += zp[j] * (1.0f - f);
            a1 += zp[j] * f;
        }
#pragma unroll
        for (int off = 32; off >= 1; off >>= 1) {
            a0 += __shfl_xor(a0, off, 64);
            a1 += __shfl_xor(a1, off, 64);
        }
        if (lane == 0) M[chunk] = make_float2(a0, a1);
    } else {
        __shared__ v2u sortedP[EPB];           // 64 KiB
        __shared__ unsigned cur[NSUB], gb[NSUB];
        __shared__ unsigned wsum[8], wbase[8];
        int blk = b - 2048;
        int base = blk * EPB;
        // hoist all streaming loads upfront
        v4i r[4], c[4];
        v4f v[4];
#pragma unroll
        for (int j = 0; j < 4; ++j) {
            int e = base + j * 2048 + t * 4;
            r[j] = __builtin_nontemporal_load((const v4i*)(rows + e));
            c[j] = __builtin_nontemporal_load((const v4i*)(cols + e));
            v[j] = __builtin_nontemporal_load((const v4f*)(vals + e));
        }
        cur[t] = 0u;
        __syncthreads();
        // local histogram by sub-bucket
#pragma unroll
        for (int j = 0; j < 4; ++j) {
            const int* rp = (const int*)&r[j];
            const int* cp = (const int*)&c[j];
#pragma unroll
            for (int kk = 0; kk < 4; ++kk) {
                unsigned sub = (((unsigned)rp[kk] >> 14) << 1) | ((unsigned)cp[kk] >> 21);
                atomicAdd(&cur[sub], 1u);
            }
        }
        __syncthreads();
        // scan local hist (512 counters, 512 threads)
        unsigned lv = cur[t];
        unsigned lincl = lv;
#pragma unroll
        for (int off = 1; off < 64; off <<= 1) {
            unsigned n = __shfl_up(lincl, off, 64);
            if ((t & 63) >= off) lincl += n;
        }
        if ((t & 63) == 63) wsum[t >> 6] = lincl;
        __syncthreads();
        if (t == 0) {
            unsigned a = 0;
            for (int i = 0; i < 8; ++i) { wbase[i] = a; a += wsum[i]; }
        }
        __syncthreads();
        {
            unsigned lexcl = wbase[t >> 6] + lincl - lv;
            gb[t] = (unsigned)t * CAP_SUB + atomicAdd(&subCtr[t], lv) - lexcl;
            cur[t] = lexcl;
        }
        __syncthreads();
        // place, sorted by sub-bucket; sub id packed into ent.y bits [4:12]
#pragma unroll
        for (int j = 0; j < 4; ++j) {
            const int* rp = (const int*)&r[j];
            const int* cp = (const int*)&c[j];
            const float* vp = (const float*)&v[j];
#pragma unroll
            for (int kk = 0; kk < 4; ++kk) {
                unsigned row = (unsigned)rp[kk], col = (unsigned)cp[kk];
                unsigned sub = ((row >> 14) << 1) | (col >> 21);
                unsigned rl = row & 16383u;
                v2u ent;
                ent.x = col | ((rl & 0x3FFu) << 22);
                ent.y = (rl >> 10) | (sub << 4) | ((unsigned)f2bf(vp[kk]) << 16);
                unsigned i = atomicAdd(&cur[sub], 1u);
                sortedP[i] = ent;
            }
        }
        __syncthreads();
        // coalesced write-out (sub recovered from packed bits; kE ignores them)
#pragma unroll
        for (int k = 0; k < 16; ++k) {
            int i = k * 512 + t;
            v2u e = sortedP[i];
            unsigned bkt = (e.y >> 4) & 0x1FFu;
            __builtin_nontemporal_store(e, rowBinned + gb[bkt] + i);
        }
    }
}

// ============ kB: level sums
__global__ __launch_bounds__(256) void kB(const float2* __restrict__ M,
                                          const float* __restrict__ V,
                                          float* __restrict__ S) {
    int b = blockIdx.x, t = threadIdx.x;
    int lvl = b >> 3, slice = b & 7;
    const float2* Vl = (const float2*)(V + lvl * COARSE * 2);
    float s0 = 0.f, s1 = 0.f;
    int c0 = slice * 2048 + t * 8;
#pragma unroll
    for (int cc = 0; cc < 8; ++cc) {
        int c = c0 + cc;
        float2 m = M[c];
        int k = (c > 0) ? ((c - 1) >> 1) : 0;
        int kp = min(k + 1, COARSE - 1);
        float2 vk = Vl[k], vkp = Vl[kp];
        s0 += vk.x * m.x + vkp.x * m.y;
        s1 += vk.y * m.x + vkp.y * m.y;
    }
    int gw = min(1 << (10 - lvl), 64);
    for (int sh = gw >> 1; sh >= 1; sh >>= 1) {
        s0 += __shfl_xor(s0, sh, 64);
        s1 += __shfl_xor(s1, sh, 64);
    }
    if ((t & (gw - 1)) == 0) {
        int bb = c0 >> (13 - lvl);
        int soff = (2 << lvl) - 2;
        unsafeAtomicAdd(&S[(soff + bb) * 2 + 0], s0);
        unsafeAtomicAdd(&S[(soff + bb) * 2 + 1], s1);
    }
}

// ============ kCw: w = diag*z + lowrank -> bf16  (no LDS -> full occupancy)
__global__ __launch_bounds__(512) void kCw(const float* __restrict__ diag,
                                           const float* __restrict__ z,
                                           const float* __restrict__ S,
                                           const float* __restrict__ U,
                                           unsigned short* __restrict__ wb) {
    int b = blockIdx.x, t = threadIdx.x;
    int tid = b * 512 + t;
    int base = tid * 4;
    int c = base >> 8;                // wave-uniform chunk
    int k = (c > 0) ? ((c - 1) >> 1) : 0;
    int kp = min(k + 1, COARSE - 1);
    float g0 = 0.f, g1 = 0.f;
#pragma unroll
    for (int lvl = 0; lvl < LEVELS; ++lvl) {
        int sib = (c >> (13 - lvl)) ^ 1;
        int soff = (2 << lvl) - 2;
        float2 s2 = ((const float2*)S)[soff + sib];
        const float2* Ul = (const float2*)(U + lvl * COARSE * 2);
        float2 uk = Ul[k], ukp = Ul[kp];
        g0 += uk.x * s2.x + uk.y * s2.y;
        g1 += ukp.x * s2.x + ukp.y * s2.y;
    }
    float4 d4 = *(const float4*)(diag + base);
    float4 z4 = *(const float4*)(z + base);
    const float* dp = (const float*)&d4;
    const float* zp = (const float*)&z4;
    ushort4 h4;
    unsigned short* hp = (unsigned short*)&h4;
#pragma unroll
    for (int j = 0; j < 4; ++j) {
        float p = ((float)(base + j) + 0.5f) * (1.0f / 512.0f) - 0.5f;
        p = fminf(fmaxf(p, 0.0f), (float)(COARSE - 1));
        float f = p - floorf(p);
        hp[j] = f2bf(dp[j] * zp[j] + (g0 + f * (g1 - g0)));
    }
    *(ushort4*)(wb + base) = h4;
}

// ============ kE: per row-bucket — two phases (low cols, then high cols) so the
// wb gather range per phase is 4 MiB (per-XCD L2 resident). fp32 product, LDS acc, loss.
__global__ __launch_bounds__(1024) void kE(const v2u* __restrict__ rowBinned,
                                           const unsigned* __restrict__ subCtr,
                                           const unsigned short* __restrict__ wb,
                                           const float* __restrict__ z,
                                           float* __restrict__ out) {
    __shared__ float acc[RB_SZ];          // 64 KiB
    __shared__ float red[16];
    int b = blockIdx.x, t = threadIdx.x;

    for (int i = t; i < RB_SZ / 4; i += 1024) ((float4*)acc)[i] = make_float4(0.f, 0.f, 0.f, 0.f);
    __syncthreads();

#pragma unroll 1
    for (int h = 0; h < 2; ++h) {
        int s = b * 2 + h;
        unsigned n = subCtr[s];
        const v2u* seg = rowBinned + (size_t)s * CAP_SUB;
        unsigned i = t;
        // 8-deep batches: keep 8 entry loads + 8 gathers in flight per thread
        for (; i + 7u * 1024u < n; i += 8u * 1024u) {
            v2u ev[8];
#pragma unroll
            for (int k = 0; k < 8; ++k)
                ev[k] = __builtin_nontemporal_load(seg + i + (unsigned)k * 1024u);
            unsigned short wv[8];
#pragma unroll
            for (int k = 0; k < 8; ++k)
                wv[k] = wb[ev[k].x & 0x3FFFFFu];
#pragma unroll
            for (int k = 0; k < 8; ++k) {
                unsigned rl = (ev[k].x >> 22) | ((ev[k].y & 0xFu) << 10);
                float p = bf2f((unsigned short)(ev[k].y >> 16)) * bf2f(wv[k]);
                atomicAdd(&acc[rl], p);
            }
        }
        for (; i < n; i += 1024u) {
            v2u e = __builtin_nontemporal_load(seg + i);
            unsigned rl = (e.x >> 22) | ((e.y & 0xFu) << 10);
            float p = bf2f((unsigned short)(e.y >> 16)) * bf2f(wb[e.x & 0x3FFFFFu]);
            atomicAdd(&acc[rl], p);
        }
    }
    __syncthreads();

    float part = 0.f;
    int gbase = b * RB_SZ;
    for (int k = t; k < RB_SZ; k += 1024) {
        float d = acc[k] - z[gbase + k];
        part += d * d;
    }
#pragma unroll
    for (int off = 32; off >= 1; off >>= 1) part += __shfl_xor(part, off, 64);
    if ((t & 63) == 0) red[t >> 6] = part;
    __syncthreads();
    if (t == 0) {
        float s = 0.f;
        for (int k = 0; k < 16; ++k) s += red[k];
        unsafeAtomicAdd(out, s * (1.0f / (float)N_NODES));
    }
}

extern "C" void kernel_launch(void* const* d_in, const int* in_sizes, int n_in,
                              void* d_out, int out_size, void* d_ws, size_t ws_size,
                              hipStream_t stream) {
    const float* diag  = (const float*)d_in[0];
    const float* U     = (const float*)d_in[1];
    const float* V     = (const float*)d_in[2];
    const float* Avals = (const float*)d_in[3];
    const float* z     = (const float*)d_in[4];
    const int*   Aidx  = (const int*)d_in[5];
    const int* rows = Aidx;
    const int* cols = Aidx + NNZ_E;

    char* ws = (char*)d_ws;
    size_t off = 0;
    unsigned short* wb  = (unsigned short*)(ws + off); off += (size_t)N_NODES * 2;         // 8 MiB
    v2u* rowBinned      = (v2u*)(ws + off);            off += (size_t)NSUB * CAP_SUB * 8;  // 73.4 MiB
    unsigned* subCtr    = (unsigned*)(ws + off);       off += NSUB * 4;
    float2* M           = (float2*)(ws + off);         off += (size_t)(N_NODES / 256) * 8; // 128 KiB
    float* S            = (float*)(ws + off);          off += 16384;

    hipMemsetAsync(subCtr, 0, NSUB * 4, stream);
    kA<<<3072, 512, 0, stream>>>(z, M, S, (float*)d_out, rows, cols, Avals, subCtr, rowBinned);
    kB<<<80, 256, 0, stream>>>(M, V, S);
    kCw<<<2048, 512, 0, stream>>>(diag, z, S, U, wb);
    kE<<<NB, 1024, 0, stream>>>(rowBinned, subCtr, wb, z, (float*)d_out);
}